// Round 8
// baseline (2610.632 us; speedup 1.0000x reference)
//
#include <hip/hip_runtime.h>
#include <hip/hip_bf16.h>

typedef __bf16 bf16;
typedef __attribute__((ext_vector_type(8))) __bf16 bf16x8;
typedef __attribute__((ext_vector_type(4))) __bf16 bf16x4;
typedef __attribute__((ext_vector_type(4))) float f32x4;

#define TOKENS 15360   // B*S = 16*960
#define HID    512
#define FFN_D  2048
#define QKV_D  1536

// ---------------------------------------------------------------------------
// fast exact-GELU: A&S 7.1.26 erf (|eps|<=1.5e-7), hw exp + hw rcp
// ---------------------------------------------------------------------------
__device__ __forceinline__ float gelu_erf(float x) {
  const float z = fabsf(x) * 0.70710678118654752f;
#if __has_builtin(__builtin_amdgcn_rcpf)
  const float t = __builtin_amdgcn_rcpf(fmaf(0.3275911f, z, 1.f));
#else
  const float t = 1.f / fmaf(0.3275911f, z, 1.f);
#endif
  float p = fmaf(1.061405429f, t, -1.453152027f);
  p = fmaf(p, t, 1.421413741f);
  p = fmaf(p, t, -0.284496736f);
  p = fmaf(p, t, 0.254829592f);
  p *= t;
  const float e  = __expf(-z * z);
  const float er = fmaf(-p, e, 1.f);          // erf(|x|/sqrt2)
  return 0.5f * x * (1.f + copysignf(er, x));
}

// ---------------------------------------------------------------------------
// W fp32 [L][N][K] -> bf16 in MFMA B-fragment order:
//   group g (8 elems) = ((strip*CK + ck)*4 + j)*64 + t;  t = lane = qd*16+li
//   n = strip*64 + j*16 + (t&15);  k = ck*32 + (t>>4)*8 (+u)
// A wave's frag load becomes one coalesced b128: base + lane*16B.
// blockIdx.y = layer.  CK = K/32 (power of 2; lgCK passed).
// ---------------------------------------------------------------------------
__global__ __launch_bounds__(256) void wswz_kernel(const float* __restrict__ src,
                                                   bf16* __restrict__ dst,
                                                   int K, int lgCK, int NK) {
  const int l = blockIdx.y;
  const int g = blockIdx.x * 256 + threadIdx.x;   // group id within layer
  const int t     = g & 63;
  const int j     = (g >> 6) & 3;
  const int ck    = (g >> 8) & ((1 << lgCK) - 1);
  const int strip = g >> (8 + lgCK);
  const int n = strip * 64 + j * 16 + (t & 15);
  const int k = ck * 32 + (t >> 4) * 8;
  const float* s = src + (size_t)l * NK + (size_t)n * K + k;
  const float4 a = *(const float4*)s;
  const float4 b = *(const float4*)(s + 4);
  bf16x8 o = {(bf16)a.x, (bf16)a.y, (bf16)a.z, (bf16)a.w,
              (bf16)b.x, (bf16)b.y, (bf16)b.z, (bf16)b.w};
  *(bf16x8*)(dst + (size_t)l * NK + (size_t)g * 8) = o;
}

// ---------------------------------------------------------------------------
// GEMM: C[M,N] = A[M,K] @ W[N,K]^T (+bias fp32, + residual / GELU)
// 128x128 tile, BK=64, 4 waves, 4x4 mfma_f32_16x16x32_bf16 each.
// A staged via global_load_lds (16 KB, XOR-swizzled); W NOT in LDS — read as
// pre-swizzled B-fragments straight from global (L2-resident, coalesced
// lane*16B). Halves LDS port traffic (the measured MfmaUtil~20% ceiling came
// from LDS port: ~4x MFMA time at 16 reads/wave/iter + staging writes).
// R4/R5/R6 lessons: no pointer hoisting, no runtime-div swizzle, scalar
// epilogue (every VGPR above ~80 costs more occupancy than it saves VALU).
// ---------------------------------------------------------------------------
#define EPI_BIAS_BF16     0
#define EPI_BIAS_RES      1
#define EPI_BIAS_GELU     2

template <int EPI>
__global__ __launch_bounds__(256) void gemm_bt(
    const bf16* __restrict__ A, const bf16* __restrict__ W,
    const float* __restrict__ bias, const bf16* __restrict__ R,
    bf16* __restrict__ out, int M, int N, int K) {
  __shared__ __align__(16) bf16 As[128 * 64];

  const int tid  = threadIdx.x;
  const int lane = tid & 63;
  const int wv   = tid >> 6;
  const int li   = lane & 15;
  const int qd   = lane >> 4;
  const int mw   = (wv & 1) << 6;
  const int nw   = (wv >> 1) << 6;
  const int m0   = blockIdx.x << 7;
  const int n0   = blockIdx.y << 7;

  f32x4 acc[4][4];
#pragma unroll
  for (int i = 0; i < 4; ++i)
#pragma unroll
    for (int j = 0; j < 4; ++j) acc[i][j] = (f32x4){0.f, 0.f, 0.f, 0.f};

  const bf16* Abase = A + (size_t)m0 * K;
  const int   CK    = K >> 5;
  // wave's W strip: 64 n-cols; strip stride = CK*2048 elements
  const bf16* Wst = W + (((size_t)((n0 >> 6) + (wv >> 1)) * CK) << 11);

  for (int k0 = 0; k0 < K; k0 += 64) {
#pragma unroll
    for (int it = 0; it < 4; ++it) {
      const int fc   = it * 256 + tid;       // A chunk: row r, slot c
      const int r    = fc >> 3;
      const int c    = fc & 7;
      const int koff = (c ^ (r & 7)) << 3;   // swizzled k-chunk
      const bf16* asrc = Abase + (size_t)r * K + k0 + koff;
      bf16* adst = As + (size_t)(it * 256 + (tid & 192)) * 8;  // wave-uniform
      __builtin_amdgcn_global_load_lds(
          (const __attribute__((address_space(1))) unsigned int*)asrc,
          (__attribute__((address_space(3))) unsigned int*)adst, 16, 0, 0);
    }
    __syncthreads();

#pragma unroll
    for (int ks = 0; ks < 2; ++ks) {
      const int ck  = (ks << 2) + qd;        // A frag k-chunk (quad-encoded)
      const int ckk = (k0 >> 5) + ks;        // global k/32 chunk for W
      bf16x8 af[4], bfv[4];
#pragma unroll
      for (int i = 0; i < 4; ++i) {
        const int mr = mw + i * 16 + li;     // mr&7 == li&7
        af[i] = *(const bf16x8*)(As + mr * 64 + ((ck ^ (li & 7)) << 3));
      }
#pragma unroll
      for (int j = 0; j < 4; ++j)
        bfv[j] = *(const bf16x8*)(Wst + ((((ckk << 2) + j) << 9) + (lane << 3)));
#pragma unroll
      for (int i = 0; i < 4; ++i)
#pragma unroll
        for (int j = 0; j < 4; ++j)
          acc[i][j] = __builtin_amdgcn_mfma_f32_16x16x32_bf16(af[i], bfv[j],
                                                              acc[i][j], 0, 0, 0);
    }
    __syncthreads();
  }

  // epilogue: C/D layout col=lane&15, row=(lane>>4)*4+reg  [m89/m91 verified]
#pragma unroll
  for (int i = 0; i < 4; ++i) {
    const int mrow = m0 + mw + i * 16 + qd * 4;
#pragma unroll
    for (int j = 0; j < 4; ++j) {
      const int ncol = n0 + nw + j * 16 + li;
      const float bv = bias[ncol];
#pragma unroll
      for (int r = 0; r < 4; ++r) {
        const size_t off = (size_t)(mrow + r) * N + ncol;
        float v = acc[i][j][r] + bv;
        if (EPI == EPI_BIAS_RES) {
          out[off] = (bf16)(v + (float)R[off]);
        } else if (EPI == EPI_BIAS_GELU) {
          out[off] = (bf16)gelu_erf(v);
        } else {
          out[off] = (bf16)v;
        }
      }
    }
  }
}

// ---------------------------------------------------------------------------
// MFMA attention: one block (4 waves) per (sequence, head).
// P padded to PP (16-mult) for tiles; K-dim of PV padded to PK (32-mult).
// ---------------------------------------------------------------------------
template <int P>
__global__ __launch_bounds__(256) void attn_kernel(const bf16* __restrict__ qkv,
                                                   bf16* __restrict__ out) {
  constexpr int PP   = ((P + 15) / 16) * 16;   // 32, 48, 96
  constexpr int PK   = ((PP + 31) / 32) * 32;  // 32, 64, 96
  constexpr int MT   = PP / 16;
  constexpr int SSTR = PP + 2;                 // fp32 words
  constexpr int VSTR = PK + 8;                 // bf16 elems; *2B is 16B-mult
  constexpr int PSTR = PK + 8;

  __shared__ __align__(16) bf16 QK[2 * PP * 64];  // Q | K ; reused as Ps
  __shared__ __align__(16) bf16 Vt[64 * VSTR];
  __shared__ __align__(16) float Sm[PP * SSTR];
  __shared__ float rsum[PP];

  bf16* Qs = QK;
  bf16* Ks = QK + PP * 64;
  bf16* Ps = QK;  // overlays Q/K after S phase (dead by then)

  const int tid  = threadIdx.x;
  const int lane = tid & 63;
  const int wv   = tid >> 6;
  const int li   = lane & 15;
  const int qd   = lane >> 4;
  const int n    = blockIdx.x >> 3;
  const int h    = blockIdx.x & 7;
  const bf16* base = qkv + (size_t)n * P * QKV_D + h * 64;

  // stage Q,K: 16B chunks, slot = c ^ (r&7)
  for (int t = tid; t < P * 8; t += 256) {
    const int r = t >> 3, c = t & 7;
    const bf16x8 qv = *(const bf16x8*)(base + (size_t)r * QKV_D + c * 8);
    const bf16x8 kv = *(const bf16x8*)(base + (size_t)r * QKV_D + 512 + c * 8);
    *(bf16x8*)(Qs + r * 64 + ((c ^ (r & 7)) * 8)) = qv;
    *(bf16x8*)(Ks + r * 64 + ((c ^ (r & 7)) * 8)) = kv;
  }
  // stage V^T
  for (int t = tid; t < P * 8; t += 256) {
    const int j = t % P, dc = t / P;
    const bf16x8 vv = *(const bf16x8*)(base + (size_t)j * QKV_D + 1024 + dc * 8);
#pragma unroll
    for (int u = 0; u < 8; ++u) Vt[(dc * 8 + u) * VSTR + j] = vv[u];
  }
  if constexpr (PK > P) {
    for (int t = tid; t < 64 * (PK - P); t += 256) {
      const int d = t / (PK - P), j = P + t % (PK - P);
      Vt[d * VSTR + j] = (bf16)0.f;
    }
  }
  __syncthreads();

  // S = Q K^T
  for (int t = wv; t < MT * MT; t += 4) {
    const int ti = t / MT, tj = t % MT;
    f32x4 acc = (f32x4){0.f, 0.f, 0.f, 0.f};
#pragma unroll
    for (int ks = 0; ks < 2; ++ks) {
      const int ck = ks * 4 + qd;
      const int ar = ti * 16 + li;
      const int br = tj * 16 + li;
      const bf16x8 af = *(const bf16x8*)(Qs + ar * 64 + ((ck ^ (ar & 7)) * 8));
      const bf16x8 bv = *(const bf16x8*)(Ks + br * 64 + ((ck ^ (br & 7)) * 8));
      acc = __builtin_amdgcn_mfma_f32_16x16x32_bf16(af, bv, acc, 0, 0, 0);
    }
#pragma unroll
    for (int r = 0; r < 4; ++r)
      Sm[(ti * 16 + qd * 4 + r) * SSTR + tj * 16 + li] = acc[r];
  }
  __syncthreads();

  // softmax row: unnormalized exp -> bf16 Ps; 1/sum saved for O-write
  if (tid < P) {
    const float* srow = Sm + tid * SSTR;
    bf16* prow = Ps + tid * PSTR;
    float mx = -1e30f;
    for (int j = 0; j < P; ++j) mx = fmaxf(mx, srow[j]);
    mx *= 0.125f;  // 1/sqrt(64)
    float sum = 0.f;
    for (int j = 0; j < P; ++j) {
      const float e = __expf(srow[j] * 0.125f - mx);
      sum += e;
      prow[j] = (bf16)e;
    }
    for (int j = P; j < PK; ++j) prow[j] = (bf16)0.f;
    rsum[tid] = 1.f / sum;
  }
  __syncthreads();

  // O = P V
  for (int t = wv; t < MT * 4; t += 4) {
    const int ti = t >> 2, td = t & 3;
    f32x4 acc = (f32x4){0.f, 0.f, 0.f, 0.f};
#pragma unroll
    for (int ks = 0; ks < PK / 32; ++ks) {
      const int ck = ks * 4 + qd;
      const bf16x8 af = *(const bf16x8*)(Ps + (ti * 16 + li) * PSTR + ck * 8);
      const bf16x8 bv = *(const bf16x8*)(Vt + (td * 16 + li) * VSTR + ck * 8);
      acc = __builtin_amdgcn_mfma_f32_16x16x32_bf16(af, bv, acc, 0, 0, 0);
    }
#pragma unroll
    for (int r = 0; r < 4; ++r) {
      const int row = ti * 16 + qd * 4 + r;
      if (row < P)
        out[(size_t)(n * P + row) * HID + h * 64 + td * 16 + li] =
            (bf16)(acc[r] * rsum[row]);
    }
  }
}

// ---------------------------------------------------------------------------
// LayerNorm over 512, one wave per row. Y bf16 in (one b128/lane), bf16 out.
// ---------------------------------------------------------------------------
__global__ __launch_bounds__(256) void ln_kernel(const bf16* __restrict__ Y,
                                                 const float* __restrict__ w,
                                                 const float* __restrict__ b,
                                                 bf16* __restrict__ X) {
  const int row  = blockIdx.x * 4 + (threadIdx.x >> 6);
  const int lane = threadIdx.x & 63;
  const bf16x8 yv = *(const bf16x8*)(Y + (size_t)row * HID + 8 * lane);
  float v[8], s = 0.f, s2 = 0.f;
#pragma unroll
  for (int k = 0; k < 8; ++k) {
    v[k] = (float)yv[k];
    s += v[k];
    s2 += v[k] * v[k];
  }
#pragma unroll
  for (int off = 32; off > 0; off >>= 1) {
    s  += __shfl_xor(s, off, 64);
    s2 += __shfl_xor(s2, off, 64);
  }
  const float mean = s * (1.f / 512.f);
  const float var  = s2 * (1.f / 512.f) - mean * mean;
  const float rstd = rsqrtf(var + 1e-5f);
  const float4 w0 = ((const float4*)w)[2 * lane];
  const float4 w1 = ((const float4*)w)[2 * lane + 1];
  const float4 b0 = ((const float4*)b)[2 * lane];
  const float4 b1 = ((const float4*)b)[2 * lane + 1];
  bf16x8 o;
  o[0] = (bf16)((v[0] - mean) * rstd * w0.x + b0.x);
  o[1] = (bf16)((v[1] - mean) * rstd * w0.y + b0.y);
  o[2] = (bf16)((v[2] - mean) * rstd * w0.z + b0.z);
  o[3] = (bf16)((v[3] - mean) * rstd * w0.w + b0.w);
  o[4] = (bf16)((v[4] - mean) * rstd * w1.x + b1.x);
  o[5] = (bf16)((v[5] - mean) * rstd * w1.y + b1.y);
  o[6] = (bf16)((v[6] - mean) * rstd * w1.z + b1.z);
  o[7] = (bf16)((v[7] - mean) * rstd * w1.w + b1.w);
  *(bf16x8*)(X + (size_t)row * HID + 8 * lane) = o;
}

// ---------------------------------------------------------------------------
// input projection: h[r,o] = sum_k x[r,k]*w[o,k] + b[o], K=7. Writes the same
// value to nbr consecutive [TOKENS,HID] slices (branches share the input).
// ---------------------------------------------------------------------------
__global__ __launch_bounds__(256) void inproj_kernel(const float* __restrict__ x,
                                                     const float* __restrict__ w,
                                                     const float* __restrict__ b,
                                                     bf16* __restrict__ h,
                                                     int nbr) {
  const int idx = blockIdx.x * 256 + threadIdx.x;
  const int r = idx >> 9, o = idx & 511;
  float s = b[o];
#pragma unroll
  for (int k = 0; k < 7; ++k) s += x[r * 7 + k] * w[o * 7 + k];
  const bf16 bv = (bf16)s;
  for (int q = 0; q < nbr; ++q) h[idx + (size_t)q * TOKENS * HID] = bv;
}

// acc[row] (+)= X[row,:] . w  (per-branch final projection accumulate)
__global__ __launch_bounds__(256) void outdot_kernel(const bf16* __restrict__ X,
                                                     const float* __restrict__ w,
                                                     float* __restrict__ acc,
                                                     int first) {
  const int row  = blockIdx.x * 4 + (threadIdx.x >> 6);
  const int lane = threadIdx.x & 63;
  const bf16* xr = X + (size_t)row * HID;
  const bf16x8 xa = *(const bf16x8*)(xr + 8 * lane);
  const float4 wa = ((const float4*)w)[2 * lane];
  const float4 wb = ((const float4*)w)[2 * lane + 1];
  float s = (float)xa[0] * wa.x + (float)xa[1] * wa.y + (float)xa[2] * wa.z +
            (float)xa[3] * wa.w + (float)xa[4] * wb.x + (float)xa[5] * wb.y +
            (float)xa[6] * wb.z + (float)xa[7] * wb.w;
#pragma unroll
  for (int off = 32; off > 0; off >>= 1) s += __shfl_xor(s, off, 64);
  if (lane == 0) acc[row] = first ? s : (acc[row] + s);
}

// out[b,o] = (1/30) * sum_{j<10} acc[b*960 + o*10 + j] + b_out   (fp32 out)
__global__ __launch_bounds__(256) void pool_kernel(const float* __restrict__ acc,
                                                   const float* __restrict__ ob,
                                                   float* __restrict__ out) {
  const int idx = blockIdx.x * 256 + threadIdx.x;
  if (idx >= 16 * 96) return;
  const int bb = idx / 96, o = idx % 96;
  float s = 0.f;
#pragma unroll
  for (int j = 0; j < 10; ++j) s += acc[bb * 960 + o * 10 + j];
  out[idx] = s * (1.f / 30.f) + ob[0];
}

// ---------------------------------------------------------------------------
extern "C" void kernel_launch(void* const* d_in, const int* in_sizes, int n_in,
                              void* d_out, int out_size, void* d_ws,
                              size_t ws_size, hipStream_t stream) {
  const float* x          = (const float*)d_in[0];
  const float* ip_w       = (const float*)d_in[1];
  const float* ip_b       = (const float*)d_in[2];
  const float* in_proj_w  = (const float*)d_in[3];
  const float* in_proj_b  = (const float*)d_in[4];
  const float* out_proj_w = (const float*)d_in[5];
  const float* out_proj_b = (const float*)d_in[6];
  const float* ffn_w1     = (const float*)d_in[7];
  const float* ffn_b1     = (const float*)d_in[8];
  const float* ffn_w2     = (const float*)d_in[9];
  const float* ffn_b2     = (const float*)d_in[10];
  const float* ln1_w      = (const float*)d_in[11];
  const float* ln1_b      = (const float*)d_in[12];
  const float* ln2_w      = (const float*)d_in[13];
  const float* ln2_b      = (const float*)d_in[14];
  const float* op_w       = (const float*)d_in[15];
  const float* op_b       = (const float*)d_in[16];

  // fixed carve: weights + ACC, then activations (path-dependent)
  char* p = (char*)d_ws;
  bf16* Wq = (bf16*)p; p += (size_t)4 * QKV_D * HID * 2;
  bf16* Wo = (bf16*)p; p += (size_t)4 * HID * HID * 2;
  bf16* W1 = (bf16*)p; p += (size_t)4 * FFN_D * HID * 2;
  bf16* W2 = (bf16*)p; p += (size_t)4 * HID * FFN_D * 2;
  float* ACC = (float*)p; p += (size_t)TOKENS * 4;
  const size_t remain = ws_size - (size_t)(p - (char*)d_ws);

  const size_t T3 = 3 * (size_t)TOKENS;
  // per-token activation bytes: Y bf16 (1024) + X bf16 (1024) + SCR (4096)
  const size_t need_batched = T3 * 6144;                 // ~283 MB
  const size_t need_seq     = (size_t)TOKENS * 6144;     // ~94 MB
  const bool batched = remain >= need_batched;
  if (!batched && remain < need_seq) return;

  {  // weight conversion fp32 -> bf16, swizzled to MFMA B-fragment order
    // grid.x = N*K/8/256, grid.y = 4 layers; lgCK = log2(K/32)
    wswz_kernel<<<dim3(QKV_D * HID / 2048, 4), 256, 0, stream>>>(
        in_proj_w, Wq, HID, 4, QKV_D * HID);
    wswz_kernel<<<dim3(HID * HID / 2048, 4), 256, 0, stream>>>(
        out_proj_w, Wo, HID, 4, HID * HID);
    wswz_kernel<<<dim3(FFN_D * HID / 2048, 4), 256, 0, stream>>>(
        ffn_w1, W1, HID, 4, FFN_D * HID);
    wswz_kernel<<<dim3(HID * FFN_D / 2048, 4), 256, 0, stream>>>(
        ffn_w2, W2, FFN_D, 6, HID * FFN_D);
  }

  static const int periods[3] = {24, 48, 96};
  auto launch_attn = [&](int P, const bf16* q, bf16* o) {
    const int nblk = (TOKENS / P) * 8;
    if (P == 24)      attn_kernel<24><<<nblk, 256, 0, stream>>>(q, o);
    else if (P == 48) attn_kernel<48><<<nblk, 256, 0, stream>>>(q, o);
    else              attn_kernel<96><<<nblk, 256, 0, stream>>>(q, o);
  };

  const size_t TT = batched ? T3 : (size_t)TOKENS;
  bf16* Y   = (bf16*)p;  p += TT * HID * 2;
  bf16* X   = (bf16*)p;  p += TT * HID * 2;
  bf16* SCR = (bf16*)p;  p += TT * FFN_D * 2;
  bf16* ATT = SCR + TT * QKV_D;  // tail of SCR (qkv uses 1536 of 2048 cols)

  if (batched) {
    const int M = (int)T3, MB = M / 128;
    inproj_kernel<<<TOKENS * HID / 256, 256, 0, stream>>>(x, ip_w, ip_b, X, 3);
    for (int l = 0; l < 4; ++l) {
      gemm_bt<EPI_BIAS_BF16><<<dim3(MB, QKV_D / 128), 256, 0, stream>>>(
          X, Wq + (size_t)l * QKV_D * HID, in_proj_b + l * QKV_D, nullptr,
          SCR, M, QKV_D, HID);
      for (int br = 0; br < 3; ++br)
        launch_attn(periods[br], SCR + (size_t)br * TOKENS * QKV_D,
                    ATT + (size_t)br * TOKENS * HID);
      gemm_bt<EPI_BIAS_RES><<<dim3(MB, HID / 128), 256, 0, stream>>>(
          ATT, Wo + (size_t)l * HID * HID, out_proj_b + l * HID, X, Y,
          M, HID, HID);
      ln_kernel<<<M / 4, 256, 0, stream>>>(Y, ln1_w + l * HID, ln1_b + l * HID, X);
      gemm_bt<EPI_BIAS_GELU><<<dim3(MB, FFN_D / 128), 256, 0, stream>>>(
          X, W1 + (size_t)l * FFN_D * HID, ffn_b1 + l * FFN_D, nullptr,
          SCR, M, FFN_D, HID);
      gemm_bt<EPI_BIAS_RES><<<dim3(MB, HID / 128), 256, 0, stream>>>(
          SCR, W2 + (size_t)l * HID * FFN_D, ffn_b2 + l * HID, X, Y,
          M, HID, FFN_D);
      ln_kernel<<<M / 4, 256, 0, stream>>>(Y, ln2_w + l * HID, ln2_b + l * HID, X);
    }
    for (int br = 0; br < 3; ++br)
      outdot_kernel<<<TOKENS / 4, 256, 0, stream>>>(
          X + (size_t)br * TOKENS * HID, op_w, ACC, br == 0);
  } else {
    const int M = TOKENS, MB = M / 128;
    for (int br = 0; br < 3; ++br) {
      inproj_kernel<<<TOKENS * HID / 256, 256, 0, stream>>>(x, ip_w, ip_b, X, 1);
      for (int l = 0; l < 4; ++l) {
        gemm_bt<EPI_BIAS_BF16><<<dim3(MB, QKV_D / 128), 256, 0, stream>>>(
            X, Wq + (size_t)l * QKV_D * HID, in_proj_b + l * QKV_D, nullptr,
            SCR, M, QKV_D, HID);
        launch_attn(periods[br], SCR, ATT);
        gemm_bt<EPI_BIAS_RES><<<dim3(MB, HID / 128), 256, 0, stream>>>(
            ATT, Wo + (size_t)l * HID * HID, out_proj_b + l * HID, X, Y,
            M, HID, HID);
        ln_kernel<<<M / 4, 256, 0, stream>>>(Y, ln1_w + l * HID,
                                             ln1_b + l * HID, X);
        gemm_bt<EPI_BIAS_GELU><<<dim3(MB, FFN_D / 128), 256, 0, stream>>>(
            X, W1 + (size_t)l * FFN_D * HID, ffn_b1 + l * FFN_D, nullptr,
            SCR, M, FFN_D, HID);
        gemm_bt<EPI_BIAS_RES><<<dim3(MB, HID / 128), 256, 0, stream>>>(
            SCR, W2 + (size_t)l * HID * FFN_D, ffn_b2 + l * HID, X, Y,
            M, HID, FFN_D);
        ln_kernel<<<M / 4, 256, 0, stream>>>(Y, ln2_w + l * HID,
                                             ln2_b + l * HID, X);
      }
      outdot_kernel<<<TOKENS / 4, 256, 0, stream>>>(X, op_w, ACC, br == 0);
    }
  }
  pool_kernel<<<6, 256, 0, stream>>>(ACC, op_b, (float*)d_out);
}

// Round 9
// 2538.900 us; speedup vs baseline: 1.0283x; 1.0283x over previous
//
#include <hip/hip_runtime.h>
#include <hip/hip_bf16.h>

typedef __bf16 bf16;
typedef __attribute__((ext_vector_type(8))) __bf16 bf16x8;
typedef __attribute__((ext_vector_type(4))) __bf16 bf16x4;
typedef __attribute__((ext_vector_type(4))) float f32x4;

#define TOKENS 15360   // B*S = 16*960
#define HID    512
#define FFN_D  2048
#define QKV_D  1536

// ---------------------------------------------------------------------------
// fast exact-GELU: A&S 7.1.26 erf (|eps|<=1.5e-7), hw exp + hw rcp
// ---------------------------------------------------------------------------
__device__ __forceinline__ float gelu_erf(float x) {
  const float z = fabsf(x) * 0.70710678118654752f;
#if __has_builtin(__builtin_amdgcn_rcpf)
  const float t = __builtin_amdgcn_rcpf(fmaf(0.3275911f, z, 1.f));
#else
  const float t = 1.f / fmaf(0.3275911f, z, 1.f);
#endif
  float p = fmaf(1.061405429f, t, -1.453152027f);
  p = fmaf(p, t, 1.421413741f);
  p = fmaf(p, t, -0.284496736f);
  p = fmaf(p, t, 0.254829592f);
  p *= t;
  const float e  = __expf(-z * z);
  const float er = fmaf(-p, e, 1.f);          // erf(|x|/sqrt2)
  return 0.5f * x * (1.f + copysignf(er, x));
}

// ---------------------------------------------------------------------------
// fp32 -> bf16 weight conversion (run every launch; ws is re-poisoned)
// ---------------------------------------------------------------------------
__global__ __launch_bounds__(256) void cvt_kernel(const float* __restrict__ src,
                                                  bf16* __restrict__ dst, int n4) {
  const int i = (blockIdx.x * 256 + threadIdx.x);
  if (i >= n4) return;
  const float4 v = ((const float4*)src)[i];
  bf16x4 d = {(bf16)v.x, (bf16)v.y, (bf16)v.z, (bf16)v.w};
  *(bf16x4*)(dst + (size_t)i * 4) = d;
}

// ---------------------------------------------------------------------------
// Shared GEMM K-loop (R3/R7-verified best: 80-92 VGPR, LDS-latency-class
// staging). Lessons pinned across rounds:
//  R4: no staging-pointer hoist. R5: no runtime-div swizzle. R6: launch-bound
//  min-waves doesn't cap VGPR. R8: W must stay in LDS (global B-frags expose
//  ~200cyc L2 latency -> MfmaUtil 19.6->13.9, 65->93us).
// ---------------------------------------------------------------------------
#define EPI_BIAS_BF16     0
#define EPI_BIAS_RES      1
#define EPI_BIAS_GELU     2

#define GEMM_PROLOG                                                            \
  __shared__ __align__(16) bf16 As[128 * 64];                                  \
  __shared__ __align__(16) bf16 Bs[128 * 64];                                  \
  const int tid  = threadIdx.x;                                                \
  const int lane = tid & 63;                                                   \
  const int wv   = tid >> 6;                                                   \
  const int li   = lane & 15;                                                  \
  const int qd   = lane >> 4;                                                  \
  const int mw   = (wv & 1) << 6;                                              \
  const int nw   = (wv >> 1) << 6;                                             \
  const int m0   = blockIdx.x << 7;                                            \
  const int n0   = blockIdx.y << 7;                                            \
  f32x4 acc[4][4];                                                             \
  _Pragma("unroll") for (int i = 0; i < 4; ++i)                                \
    _Pragma("unroll") for (int j = 0; j < 4; ++j)                              \
      acc[i][j] = (f32x4){0.f, 0.f, 0.f, 0.f};

#define GEMM_KLOOP(KLEN)                                                       \
  for (int k0 = 0; k0 < (KLEN); k0 += 64) {                                    \
    _Pragma("unroll") for (int it = 0; it < 4; ++it) {                         \
      const int fc   = it * 256 + tid;                                         \
      const int r    = fc >> 3;                                                \
      const int c    = fc & 7;                                                 \
      const int koff = (c ^ (r & 7)) << 3;                                     \
      const bf16* asrc = Abase + (size_t)r * K + k0 + koff;                    \
      const bf16* bsrc = Wbase + (size_t)r * K + k0 + koff;                    \
      bf16* adst = As + (size_t)(it * 256 + (tid & 192)) * 8;                  \
      bf16* bdst = Bs + (size_t)(it * 256 + (tid & 192)) * 8;                  \
      __builtin_amdgcn_global_load_lds(                                        \
          (const __attribute__((address_space(1))) unsigned int*)asrc,         \
          (__attribute__((address_space(3))) unsigned int*)adst, 16, 0, 0);    \
      __builtin_amdgcn_global_load_lds(                                        \
          (const __attribute__((address_space(1))) unsigned int*)bsrc,         \
          (__attribute__((address_space(3))) unsigned int*)bdst, 16, 0, 0);    \
    }                                                                          \
    __syncthreads();                                                           \
    _Pragma("unroll") for (int ks = 0; ks < 2; ++ks) {                         \
      const int ck = (ks << 2) + qd;                                           \
      bf16x8 af[4], bfv[4];                                                    \
      _Pragma("unroll") for (int i = 0; i < 4; ++i) {                          \
        const int mr = mw + i * 16 + li;                                       \
        af[i] = *(const bf16x8*)(As + mr * 64 + ((ck ^ (li & 7)) << 3));       \
      }                                                                        \
      _Pragma("unroll") for (int j = 0; j < 4; ++j) {                          \
        const int nr = nw + j * 16 + li;                                       \
        bfv[j] = *(const bf16x8*)(Bs + nr * 64 + ((ck ^ (li & 7)) << 3));      \
      }                                                                        \
      _Pragma("unroll") for (int i = 0; i < 4; ++i)                            \
        _Pragma("unroll") for (int j = 0; j < 4; ++j)                          \
          acc[i][j] = __builtin_amdgcn_mfma_f32_16x16x32_bf16(                 \
              af[i], bfv[j], acc[i][j], 0, 0, 0);                              \
    }                                                                          \
    __syncthreads();                                                           \
  }

template <int EPI>
__global__ __launch_bounds__(256) void gemm_bt(
    const bf16* __restrict__ A, const bf16* __restrict__ W,
    const float* __restrict__ bias, const bf16* __restrict__ R,
    bf16* __restrict__ out, int M, int N, int K) {
  GEMM_PROLOG
  const bf16* Abase = A + (size_t)m0 * K;
  const bf16* Wbase = W + (size_t)n0 * K;
  GEMM_KLOOP(K)
  // epilogue: C/D layout col=lane&15, row=(lane>>4)*4+reg  [m89/m91 verified]
#pragma unroll
  for (int i = 0; i < 4; ++i) {
    const int mrow = m0 + mw + i * 16 + qd * 4;
#pragma unroll
    for (int j = 0; j < 4; ++j) {
      const int ncol = n0 + nw + j * 16 + li;
      const float bv = bias[ncol];
#pragma unroll
      for (int r = 0; r < 4; ++r) {
        const size_t off = (size_t)(mrow + r) * N + ncol;
        float v = acc[i][j][r] + bv;
        if (EPI == EPI_BIAS_RES) {
          out[off] = (bf16)(v + (float)R[off]);
        } else if (EPI == EPI_BIAS_GELU) {
          out[off] = (bf16)gelu_erf(v);
        } else {
          out[off] = (bf16)v;
        }
      }
    }
  }
}

// Split-K partial GEMM: blockIdx.z selects K-slice [z*Klen, (z+1)*Klen);
// writes raw fp32 partials (no bias/residual loads) at outP + z*M*ldP with
// row stride ldP floats. Bias/residual/reduction are fused into ln_fused.
__global__ __launch_bounds__(256) void gemm_part(
    const bf16* __restrict__ A, const bf16* __restrict__ W,
    float* __restrict__ outP, int ldP, int M, int N, int K, int Klen) {
  GEMM_PROLOG
  const int koff = blockIdx.z * Klen;
  outP += (size_t)blockIdx.z * M * ldP;
  const bf16* Abase = A + (size_t)m0 * K + koff;
  const bf16* Wbase = W + (size_t)n0 * K + koff;
  GEMM_KLOOP(Klen)
#pragma unroll
  for (int i = 0; i < 4; ++i) {
    const int mrow = m0 + mw + i * 16 + qd * 4;
#pragma unroll
    for (int j = 0; j < 4; ++j) {
      const int ncol = n0 + nw + j * 16 + li;
#pragma unroll
      for (int r = 0; r < 4; ++r)
        outP[(size_t)(mrow + r) * ldP + ncol] = acc[i][j][r];
    }
  }
}

// ---------------------------------------------------------------------------
// MFMA attention: one block (4 waves) per (sequence, head).
// ---------------------------------------------------------------------------
template <int P>
__global__ __launch_bounds__(256) void attn_kernel(const bf16* __restrict__ qkv,
                                                   bf16* __restrict__ out) {
  constexpr int PP   = ((P + 15) / 16) * 16;   // 32, 48, 96
  constexpr int PK   = ((PP + 31) / 32) * 32;  // 32, 64, 96
  constexpr int MT   = PP / 16;
  constexpr int SSTR = PP + 2;
  constexpr int VSTR = PK + 8;
  constexpr int PSTR = PK + 8;

  __shared__ __align__(16) bf16 QK[2 * PP * 64];
  __shared__ __align__(16) bf16 Vt[64 * VSTR];
  __shared__ __align__(16) float Sm[PP * SSTR];
  __shared__ float rsum[PP];

  bf16* Qs = QK;
  bf16* Ks = QK + PP * 64;
  bf16* Ps = QK;

  const int tid  = threadIdx.x;
  const int lane = tid & 63;
  const int wv   = tid >> 6;
  const int li   = lane & 15;
  const int qd   = lane >> 4;
  const int n    = blockIdx.x >> 3;
  const int h    = blockIdx.x & 7;
  const bf16* base = qkv + (size_t)n * P * QKV_D + h * 64;

  for (int t = tid; t < P * 8; t += 256) {
    const int r = t >> 3, c = t & 7;
    const bf16x8 qv = *(const bf16x8*)(base + (size_t)r * QKV_D + c * 8);
    const bf16x8 kv = *(const bf16x8*)(base + (size_t)r * QKV_D + 512 + c * 8);
    *(bf16x8*)(Qs + r * 64 + ((c ^ (r & 7)) * 8)) = qv;
    *(bf16x8*)(Ks + r * 64 + ((c ^ (r & 7)) * 8)) = kv;
  }
  for (int t = tid; t < P * 8; t += 256) {
    const int j = t % P, dc = t / P;
    const bf16x8 vv = *(const bf16x8*)(base + (size_t)j * QKV_D + 1024 + dc * 8);
#pragma unroll
    for (int u = 0; u < 8; ++u) Vt[(dc * 8 + u) * VSTR + j] = vv[u];
  }
  if constexpr (PK > P) {
    for (int t = tid; t < 64 * (PK - P); t += 256) {
      const int d = t / (PK - P), j = P + t % (PK - P);
      Vt[d * VSTR + j] = (bf16)0.f;
    }
  }
  __syncthreads();

  for (int t = wv; t < MT * MT; t += 4) {
    const int ti = t / MT, tj = t % MT;
    f32x4 acc = (f32x4){0.f, 0.f, 0.f, 0.f};
#pragma unroll
    for (int ks = 0; ks < 2; ++ks) {
      const int ck = ks * 4 + qd;
      const int ar = ti * 16 + li;
      const int br = tj * 16 + li;
      const bf16x8 af = *(const bf16x8*)(Qs + ar * 64 + ((ck ^ (ar & 7)) * 8));
      const bf16x8 bv = *(const bf16x8*)(Ks + br * 64 + ((ck ^ (br & 7)) * 8));
      acc = __builtin_amdgcn_mfma_f32_16x16x32_bf16(af, bv, acc, 0, 0, 0);
    }
#pragma unroll
    for (int r = 0; r < 4; ++r)
      Sm[(ti * 16 + qd * 4 + r) * SSTR + tj * 16 + li] = acc[r];
  }
  __syncthreads();

  if (tid < P) {
    const float* srow = Sm + tid * SSTR;
    bf16* prow = Ps + tid * PSTR;
    float mx = -1e30f;
    for (int j = 0; j < P; ++j) mx = fmaxf(mx, srow[j]);
    mx *= 0.125f;
    float sum = 0.f;
    for (int j = 0; j < P; ++j) {
      const float e = __expf(srow[j] * 0.125f - mx);
      sum += e;
      prow[j] = (bf16)e;
    }
    for (int j = P; j < PK; ++j) prow[j] = (bf16)0.f;
    rsum[tid] = 1.f / sum;
  }
  __syncthreads();

  for (int t = wv; t < MT * 4; t += 4) {
    const int ti = t >> 2, td = t & 3;
    f32x4 acc = (f32x4){0.f, 0.f, 0.f, 0.f};
#pragma unroll
    for (int ks = 0; ks < PK / 32; ++ks) {
      const int ck = ks * 4 + qd;
      const bf16x8 af = *(const bf16x8*)(Ps + (ti * 16 + li) * PSTR + ck * 8);
      const bf16x8 bv = *(const bf16x8*)(Vt + (td * 16 + li) * VSTR + ck * 8);
      acc = __builtin_amdgcn_mfma_f32_16x16x32_bf16(af, bv, acc, 0, 0, 0);
    }
#pragma unroll
    for (int r = 0; r < 4; ++r) {
      const int row = ti * 16 + qd * 4 + r;
      if (row < P)
        out[(size_t)(n * P + row) * HID + h * 64 + td * 16 + li] =
            (bf16)(acc[r] * rsum[row]);
    }
  }
}

// ---------------------------------------------------------------------------
// Fused LN: y = P0(+P1) + bias + residual R; X = LN(y)*w + b.
// One wave per row. NP = number of fp32 partials. In-place R==X safe (row
// fully read into registers before the write).
// ---------------------------------------------------------------------------
template <int NP>
__global__ __launch_bounds__(256) void ln_fused(
    const float* __restrict__ P, int ldP, size_t pstride,
    const float* __restrict__ bias, const bf16* __restrict__ R,
    const float* __restrict__ w, const float* __restrict__ b,
    bf16* __restrict__ X) {
  const int row  = blockIdx.x * 4 + (threadIdx.x >> 6);
  const int lane = threadIdx.x & 63;
  const int col  = 8 * lane;
  const float* p0 = P + (size_t)row * ldP + col;
  float v[8];
  {
    const float4 a0 = *(const float4*)p0;
    const float4 a1 = *(const float4*)(p0 + 4);
    v[0] = a0.x; v[1] = a0.y; v[2] = a0.z; v[3] = a0.w;
    v[4] = a1.x; v[5] = a1.y; v[6] = a1.z; v[7] = a1.w;
  }
  if (NP == 2) {
    const float4 a0 = *(const float4*)(p0 + pstride);
    const float4 a1 = *(const float4*)(p0 + pstride + 4);
    v[0] += a0.x; v[1] += a0.y; v[2] += a0.z; v[3] += a0.w;
    v[4] += a1.x; v[5] += a1.y; v[6] += a1.z; v[7] += a1.w;
  }
  {
    const float4 b0 = *(const float4*)(bias + col);
    const float4 b1 = *(const float4*)(bias + col + 4);
    const bf16x8 rv = *(const bf16x8*)(R + (size_t)row * HID + col);
    v[0] += b0.x + (float)rv[0]; v[1] += b0.y + (float)rv[1];
    v[2] += b0.z + (float)rv[2]; v[3] += b0.w + (float)rv[3];
    v[4] += b1.x + (float)rv[4]; v[5] += b1.y + (float)rv[5];
    v[6] += b1.z + (float)rv[6]; v[7] += b1.w + (float)rv[7];
  }
  float s = 0.f, s2 = 0.f;
#pragma unroll
  for (int k = 0; k < 8; ++k) { s += v[k]; s2 += v[k] * v[k]; }
#pragma unroll
  for (int off = 32; off > 0; off >>= 1) {
    s  += __shfl_xor(s, off, 64);
    s2 += __shfl_xor(s2, off, 64);
  }
  const float mean = s * (1.f / 512.f);
  const float var  = s2 * (1.f / 512.f) - mean * mean;
  const float rstd = rsqrtf(var + 1e-5f);
  const float4 w0 = *(const float4*)(w + col);
  const float4 w1 = *(const float4*)(w + col + 4);
  const float4 g0 = *(const float4*)(b + col);
  const float4 g1 = *(const float4*)(b + col + 4);
  bf16x8 o;
  o[0] = (bf16)((v[0] - mean) * rstd * w0.x + g0.x);
  o[1] = (bf16)((v[1] - mean) * rstd * w0.y + g0.y);
  o[2] = (bf16)((v[2] - mean) * rstd * w0.z + g0.z);
  o[3] = (bf16)((v[3] - mean) * rstd * w0.w + g0.w);
  o[4] = (bf16)((v[4] - mean) * rstd * w1.x + g1.x);
  o[5] = (bf16)((v[5] - mean) * rstd * w1.y + g1.y);
  o[6] = (bf16)((v[6] - mean) * rstd * w1.z + g1.z);
  o[7] = (bf16)((v[7] - mean) * rstd * w1.w + g1.w);
  *(bf16x8*)(X + (size_t)row * HID + col) = o;
}

// ---------------------------------------------------------------------------
// LayerNorm over bf16 Y (fallback path, R7-verified).
// ---------------------------------------------------------------------------
__global__ __launch_bounds__(256) void ln_kernel(const bf16* __restrict__ Y,
                                                 const float* __restrict__ w,
                                                 const float* __restrict__ b,
                                                 bf16* __restrict__ X) {
  const int row  = blockIdx.x * 4 + (threadIdx.x >> 6);
  const int lane = threadIdx.x & 63;
  const bf16x8 yv = *(const bf16x8*)(Y + (size_t)row * HID + 8 * lane);
  float v[8], s = 0.f, s2 = 0.f;
#pragma unroll
  for (int k = 0; k < 8; ++k) {
    v[k] = (float)yv[k];
    s += v[k];
    s2 += v[k] * v[k];
  }
#pragma unroll
  for (int off = 32; off > 0; off >>= 1) {
    s  += __shfl_xor(s, off, 64);
    s2 += __shfl_xor(s2, off, 64);
  }
  const float mean = s * (1.f / 512.f);
  const float var  = s2 * (1.f / 512.f) - mean * mean;
  const float rstd = rsqrtf(var + 1e-5f);
  const float4 w0 = ((const float4*)w)[2 * lane];
  const float4 w1 = ((const float4*)w)[2 * lane + 1];
  const float4 b0 = ((const float4*)b)[2 * lane];
  const float4 b1 = ((const float4*)b)[2 * lane + 1];
  bf16x8 o;
  o[0] = (bf16)((v[0] - mean) * rstd * w0.x + b0.x);
  o[1] = (bf16)((v[1] - mean) * rstd * w0.y + b0.y);
  o[2] = (bf16)((v[2] - mean) * rstd * w0.z + b0.z);
  o[3] = (bf16)((v[3] - mean) * rstd * w0.w + b0.w);
  o[4] = (bf16)((v[4] - mean) * rstd * w1.x + b1.x);
  o[5] = (bf16)((v[5] - mean) * rstd * w1.y + b1.y);
  o[6] = (bf16)((v[6] - mean) * rstd * w1.z + b1.z);
  o[7] = (bf16)((v[7] - mean) * rstd * w1.w + b1.w);
  *(bf16x8*)(X + (size_t)row * HID + 8 * lane) = o;
}

// ---------------------------------------------------------------------------
__global__ __launch_bounds__(256) void inproj_kernel(const float* __restrict__ x,
                                                     const float* __restrict__ w,
                                                     const float* __restrict__ b,
                                                     bf16* __restrict__ h) {
  const int idx = blockIdx.x * 256 + threadIdx.x;
  const int r = idx >> 9, o = idx & 511;
  float s = b[o];
#pragma unroll
  for (int k = 0; k < 7; ++k) s += x[r * 7 + k] * w[o * 7 + k];
  h[idx] = (bf16)s;
}

__global__ __launch_bounds__(256) void outdot_kernel(const bf16* __restrict__ X,
                                                     const float* __restrict__ w,
                                                     float* __restrict__ acc,
                                                     int first) {
  const int row  = blockIdx.x * 4 + (threadIdx.x >> 6);
  const int lane = threadIdx.x & 63;
  const bf16* xr = X + (size_t)row * HID;
  const bf16x8 xa = *(const bf16x8*)(xr + 8 * lane);
  const float4 wa = ((const float4*)w)[2 * lane];
  const float4 wb = ((const float4*)w)[2 * lane + 1];
  float s = (float)xa[0] * wa.x + (float)xa[1] * wa.y + (float)xa[2] * wa.z +
            (float)xa[3] * wa.w + (float)xa[4] * wb.x + (float)xa[5] * wb.y +
            (float)xa[6] * wb.z + (float)xa[7] * wb.w;
#pragma unroll
  for (int off = 32; off > 0; off >>= 1) s += __shfl_xor(s, off, 64);
  if (lane == 0) acc[row] = first ? s : (acc[row] + s);
}

__global__ __launch_bounds__(256) void pool_kernel(const float* __restrict__ acc,
                                                   const float* __restrict__ ob,
                                                   float* __restrict__ out) {
  const int idx = blockIdx.x * 256 + threadIdx.x;
  if (idx >= 16 * 96) return;
  const int bb = idx / 96, o = idx % 96;
  float s = 0.f;
#pragma unroll
  for (int j = 0; j < 10; ++j) s += acc[bb * 960 + o * 10 + j];
  out[idx] = s * (1.f / 30.f) + ob[0];
}

// ---------------------------------------------------------------------------
extern "C" void kernel_launch(void* const* d_in, const int* in_sizes, int n_in,
                              void* d_out, int out_size, void* d_ws,
                              size_t ws_size, hipStream_t stream) {
  const float* x          = (const float*)d_in[0];
  const float* ip_w       = (const float*)d_in[1];
  const float* ip_b       = (const float*)d_in[2];
  const float* in_proj_w  = (const float*)d_in[3];
  const float* in_proj_b  = (const float*)d_in[4];
  const float* out_proj_w = (const float*)d_in[5];
  const float* out_proj_b = (const float*)d_in[6];
  const float* ffn_w1     = (const float*)d_in[7];
  const float* ffn_b1     = (const float*)d_in[8];
  const float* ffn_w2     = (const float*)d_in[9];
  const float* ffn_b2     = (const float*)d_in[10];
  const float* ln1_w      = (const float*)d_in[11];
  const float* ln1_b      = (const float*)d_in[12];
  const float* ln2_w      = (const float*)d_in[13];
  const float* ln2_b      = (const float*)d_in[14];
  const float* op_w       = (const float*)d_in[15];
  const float* op_b       = (const float*)d_in[16];

  char* p = (char*)d_ws;
  bf16* Wq = (bf16*)p; p += (size_t)4 * QKV_D * HID * 2;
  bf16* Wo = (bf16*)p; p += (size_t)4 * HID * HID * 2;
  bf16* W1 = (bf16*)p; p += (size_t)4 * FFN_D * HID * 2;
  bf16* W2 = (bf16*)p; p += (size_t)4 * HID * FFN_D * 2;
  float* ACC = (float*)p; p += (size_t)TOKENS * 4;
  const size_t remain = ws_size - (size_t)(p - (char*)d_ws);

  const size_t szX   = (size_t)TOKENS * HID * 2;        // 15.7 MB
  const size_t szSCR = (size_t)TOKENS * FFN_D * 2;      // 62.9 MB
  const size_t szP   = (size_t)2 * TOKENS * HID * 4;    // 62.9 MB (2 fp32)
  const bool split = remain >= szX + szSCR + szP;       // ~141.6 MB
  if (!split && remain < szX + szSCR + szX) return;     // fallback needs ~94 MB

  {  // weight conversion fp32 -> bf16
    const int nq = 4 * QKV_D * HID / 4, no = 4 * HID * HID / 4,
              n1 = 4 * FFN_D * HID / 4, n2 = 4 * HID * FFN_D / 4;
    cvt_kernel<<<(nq + 255) / 256, 256, 0, stream>>>(in_proj_w, Wq, nq);
    cvt_kernel<<<(no + 255) / 256, 256, 0, stream>>>(out_proj_w, Wo, no);
    cvt_kernel<<<(n1 + 255) / 256, 256, 0, stream>>>(ffn_w1, W1, n1);
    cvt_kernel<<<(n2 + 255) / 256, 256, 0, stream>>>(ffn_w2, W2, n2);
  }

  static const int periods[3] = {24, 48, 96};
  auto launch_attn = [&](int P, const bf16* q, bf16* o) {
    const int nblk = (TOKENS / P) * 8;
    if (P == 24)      attn_kernel<24><<<nblk, 256, 0, stream>>>(q, o);
    else if (P == 48) attn_kernel<48><<<nblk, 256, 0, stream>>>(q, o);
    else              attn_kernel<96><<<nblk, 256, 0, stream>>>(q, o);
  };

  bf16* X   = (bf16*)p;  p += szX;
  bf16* SCR = (bf16*)p;  p += szSCR;
  bf16* ATT = SCR + (size_t)TOKENS * QKV_D;  // tail cols 1536..2047 of SCR
  const int M = TOKENS, MB = M / 128;

  if (split) {
    // Partials: out-proj overlays the dead QKV cols of SCR (float cols
    // 0..511 of the 1024-float rows; ATT lives at float cols 768..1023).
    float* Pf = (float*)p;            // FFN2 partials, 2 x [M,512] fp32
    float* Pscr = (float*)SCR;        // out-proj partial, ldP=1024

    for (int br = 0; br < 3; ++br) {
      inproj_kernel<<<TOKENS * HID / 256, 256, 0, stream>>>(x, ip_w, ip_b, X);
      for (int l = 0; l < 4; ++l) {
        gemm_bt<EPI_BIAS_BF16><<<dim3(MB, QKV_D / 128), 256, 0, stream>>>(
            X, Wq + (size_t)l * QKV_D * HID, in_proj_b + l * QKV_D, nullptr,
            SCR, M, QKV_D, HID);
        launch_attn(periods[br], SCR, ATT);
        // out-proj -> fp32 partial in dead-QKV overlay (480 blocks, K=512)
        gemm_part<<<dim3(MB, HID / 128, 1), 256, 0, stream>>>(
            ATT, Wo + (size_t)l * HID * HID, Pscr, 1024, M, HID, HID, HID);
        ln_fused<1><<<M / 4, 256, 0, stream>>>(
            Pscr, 1024, 0, out_proj_b + l * HID, X, ln1_w + l * HID,
            ln1_b + l * HID, X);
        gemm_bt<EPI_BIAS_GELU><<<dim3(MB, FFN_D / 128), 256, 0, stream>>>(
            X, W1 + (size_t)l * FFN_D * HID, ffn_b1 + l * FFN_D, nullptr,
            SCR, M, FFN_D, HID);
        // FFN2 split-K=2: 960 blocks of 16 iters (was 480 blocks, ~1.9/CU)
        gemm_part<<<dim3(MB, HID / 128, 2), 256, 0, stream>>>(
            SCR, W2 + (size_t)l * HID * FFN_D, Pf, HID, M, HID, FFN_D,
            FFN_D / 2);
        ln_fused<2><<<M / 4, 256, 0, stream>>>(
            Pf, HID, (size_t)M * HID, ffn_b2 + l * HID, X, ln2_w + l * HID,
            ln2_b + l * HID, X);
      }
      outdot_kernel<<<TOKENS / 4, 256, 0, stream>>>(X, op_w, ACC, br == 0);
    }
  } else {
    // fallback: exact R7 structure (bf16 Y + RES epilogues)
    bf16* Y = (bf16*)p;
    for (int br = 0; br < 3; ++br) {
      inproj_kernel<<<TOKENS * HID / 256, 256, 0, stream>>>(x, ip_w, ip_b, X);
      for (int l = 0; l < 4; ++l) {
        gemm_bt<EPI_BIAS_BF16><<<dim3(MB, QKV_D / 128), 256, 0, stream>>>(
            X, Wq + (size_t)l * QKV_D * HID, in_proj_b + l * QKV_D, nullptr,
            SCR, M, QKV_D, HID);
        launch_attn(periods[br], SCR, ATT);
        gemm_bt<EPI_BIAS_RES><<<dim3(MB, HID / 128), 256, 0, stream>>>(
            ATT, Wo + (size_t)l * HID * HID, out_proj_b + l * HID, X, Y,
            M, HID, HID);
        ln_kernel<<<M / 4, 256, 0, stream>>>(Y, ln1_w + l * HID,
                                             ln1_b + l * HID, X);
        gemm_bt<EPI_BIAS_GELU><<<dim3(MB, FFN_D / 128), 256, 0, stream>>>(
            X, W1 + (size_t)l * FFN_D * HID, ffn_b1 + l * FFN_D, nullptr,
            SCR, M, FFN_D, HID);
        gemm_bt<EPI_BIAS_RES><<<dim3(MB, HID / 128), 256, 0, stream>>>(
            SCR, W2 + (size_t)l * HID * FFN_D, ffn_b2 + l * HID, X, Y,
            M, HID, FFN_D);
        ln_kernel<<<M / 4, 256, 0, stream>>>(Y, ln2_w + l * HID,
                                             ln2_b + l * HID, X);
      }
      outdot_kernel<<<TOKENS / 4, 256, 0, stream>>>(X, op_w, ACC, br == 0);
    }
  }
  pool_kernel<<<6, 256, 0, stream>>>(ACC, op_b, (float*)d_out);
}